// Round 4
// baseline (16.584 us; speedup 1.0000x reference)
//
#include <hip/hip_runtime.h>
#include <hip/hip_bf16.h>

// out[b,y,:] = sum_{a=0}^{y>>3} (k[b,y,:]·q[b,8a,:]) * v[b,8a,:]
// T=2048, anchors=256 (stride 8), E=64, fp32 in/out.
// One kernel, zero barriers: each wave owns a 16-row slab and all its anchors.
// Per anchor-tile (32 anchors): S(16x32) = K·Qa^T via MFMA, transpose S through
// a private 1.3KB LDS patch, out += S·Va via MFMA. Ping-pong prefetch of Q/V.

constexpr int T_LEN = 2048;
constexpr int EDIM  = 64;
constexpr int TE    = T_LEN * EDIM;
constexpr int SLAB  = 16;            // rows per wave
constexpr int SSTR  = 40;            // LDS S row stride in shorts (80B -> 16B-aligned b128)

typedef __attribute__((ext_vector_type(4))) float f32x4;
typedef __attribute__((ext_vector_type(8))) short bf16x8;

__device__ __forceinline__ short f2bf(float f) {
    __hip_bfloat16 h = __float2bfloat16(f);
    return __builtin_bit_cast(short, h);
}

__device__ __forceinline__ bf16x8 pack8(const f32x4& a, const f32x4& b) {
    bf16x8 r;
    r[0] = f2bf(a[0]); r[1] = f2bf(a[1]); r[2] = f2bf(a[2]); r[3] = f2bf(a[3]);
    r[4] = f2bf(b[0]); r[5] = f2bf(b[1]); r[6] = f2bf(b[2]); r[7] = f2bf(b[3]);
    return r;
}

__global__ __launch_bounds__(256, 1)
void sh2_wave(const float* __restrict__ kk, const float* __restrict__ qq,
              const float* __restrict__ vv, float* __restrict__ out, int B)
{
    __shared__ alignas(16) short slds[4][SLAB * SSTR];   // 4 x 1.25 KB, per-wave

    const int bid  = blockIdx.x;
    const int b    = bid % B;          // bid%8==b -> each XCD caches one batch
    const int blk  = bid / B;          // 0..31
    const int w    = threadIdx.x >> 6;
    const int lane = threadIdx.x & 63;
    const int g = lane >> 4, ln = lane & 15;
    const int p    = blk * 4 + w;      // slab index 0..127
    const int y0   = p * SLAB;

    const float* kb = kk + (size_t)b * TE;
    const float* qb = qq + (size_t)b * TE;
    const float* vb = vv + (size_t)b * TE;
    short* sl = slds[w];

    const int nat = ((2 * p + 1) >> 5) + 1;   // anchor-tiles for this slab (1..8)

    // K A-frags, resident for the whole slab: m = ln, k = eh*32 + 8g + i
    bf16x8 Kf[2];
    #pragma unroll
    for (int eh = 0; eh < 2; ++eh) {
        const float* pk = kb + (size_t)(y0 + ln) * EDIM + eh * 32 + g * 8;
        Kf[eh] = pack8(*(const f32x4*)pk, *(const f32x4*)(pk + 4));
    }

    const f32x4 vzero = {0.f, 0.f, 0.f, 0.f};
    f32x4 acc[4] = {vzero, vzero, vzero, vzero};

    auto LOADQ = [&](f32x4 (&qr)[2][2][2], int a0) {
        #pragma unroll
        for (int nt = 0; nt < 2; ++nt)
            #pragma unroll
            for (int eh = 0; eh < 2; ++eh) {
                const float* pq = qb + (size_t)(8 * (a0 + nt * 16 + ln)) * EDIM + eh * 32 + g * 8;
                qr[nt][eh][0] = *(const f32x4*)pq;
                qr[nt][eh][1] = *(const f32x4*)(pq + 4);
            }
    };
    auto LOADV = [&](float (&vr)[4][8], int a0) {
        const float* pv = vb + (size_t)(8 * (a0 + 8 * g)) * EDIM + ln;
        #pragma unroll
        for (int i = 0; i < 8; ++i)
            #pragma unroll
            for (int et = 0; et < 4; ++et)
                vr[et][i] = pv[(size_t)(8 * i) * EDIM + et * 16];
    };

    auto COMPUTE = [&](f32x4 (&qr)[2][2][2], float (&vr)[4][8], int ai) {
        const int a0 = ai * 32;

        // stage 1: S = K · Qa^T   (16x32 tile, two nt halves, K=64 via 2 MFMAs)
        f32x4 S[2];
        #pragma unroll
        for (int nt = 0; nt < 2; ++nt) {
            bf16x8 q0 = pack8(qr[nt][0][0], qr[nt][0][1]);
            bf16x8 q1 = pack8(qr[nt][1][0], qr[nt][1][1]);
            f32x4 s = vzero;
            s = __builtin_amdgcn_mfma_f32_16x16x32_bf16(Kf[0], q0, s, 0, 0, 0);
            s = __builtin_amdgcn_mfma_f32_16x16x32_bf16(Kf[1], q1, s, 0, 0, 0);
            S[nt] = s;
        }

        // mask partial anchors (only the last anchor-tile can be partial)
        if (ai == nat - 1) {
            #pragma unroll
            for (int nt = 0; nt < 2; ++nt)
                #pragma unroll
                for (int r = 0; r < 4; ++r) {
                    int y = y0 + g * 4 + r;
                    int a = a0 + nt * 16 + ln;
                    if (8 * a > y) S[nt][r] = 0.f;
                }
        }

        // transpose S via private LDS patch: write [row=g*4+r][a=nt*16+ln]
        #pragma unroll
        for (int nt = 0; nt < 2; ++nt)
            #pragma unroll
            for (int r = 0; r < 4; ++r)
                sl[(g * 4 + r) * SSTR + nt * 16 + ln] = f2bf(S[nt][r]);

        // read back stage-2 A-frag: m = ln (row), k = 8g + i (anchor)
        bf16x8 SA = *(const bf16x8*)(sl + ln * SSTR + 8 * g);

        // stage 2: acc += S · Va   (B-frag: n = et*16+ln (e), k = 8g+i)
        #pragma unroll
        for (int et = 0; et < 4; ++et) {
            bf16x8 Vf;
            #pragma unroll
            for (int i = 0; i < 8; ++i) Vf[i] = f2bf(vr[et][i]);
            acc[et] = __builtin_amdgcn_mfma_f32_16x16x32_bf16(SA, Vf, acc[et], 0, 0, 0);
        }
    };

    // ping-pong prefetched main loop over anchor-tiles
    f32x4 qA[2][2][2], qB[2][2][2];
    float vA[4][8], vB[4][8];
    LOADQ(qA, 0); LOADV(vA, 0);
    int ai = 0;
    while (true) {
        if (ai + 1 < nat) { LOADQ(qB, (ai + 1) * 32); LOADV(vB, (ai + 1) * 32); }
        COMPUTE(qA, vA, ai);
        if (++ai >= nat) break;
        if (ai + 1 < nat) { LOADQ(qA, (ai + 1) * 32); LOADV(vA, (ai + 1) * 32); }
        COMPUTE(qB, vB, ai);
        if (++ai >= nat) break;
    }

    // store: lane holds acc[et][r] = out[y0+g*4+r][et*16+ln]
    float* o = out + ((size_t)b * T_LEN + y0) * EDIM;
    #pragma unroll
    for (int et = 0; et < 4; ++et)
        #pragma unroll
        for (int r = 0; r < 4; ++r)
            o[(size_t)(g * 4 + r) * EDIM + et * 16 + ln] = acc[et][r];
}

extern "C" void kernel_launch(void* const* d_in, const int* in_sizes, int n_in,
                              void* d_out, int out_size, void* d_ws, size_t ws_size,
                              hipStream_t stream) {
    const float* kk = (const float*)d_in[0];
    const float* qq = (const float*)d_in[1];
    const float* vv = (const float*)d_in[2];
    float* o        = (float*)d_out;
    int B = in_sizes[0] / TE;
    sh2_wave<<<32 * B, 256, 0, stream>>>(kk, qq, vv, o, B);
}

// Round 5
// 12.186 us; speedup vs baseline: 1.3609x; 1.3609x over previous
//
#include <hip/hip_runtime.h>
#include <hip/hip_bf16.h>

// out[b,y,:] = sum_{a=0}^{y>>3} (k[b,y,:]·q[b,8a,:]) * v[b,8a,:]
// T=2048, anchors=256 (stride 8), E=64, fp32 in/out.
// One kernel, 4 waves/block: block owns complementary 32-row tile pair
// (pr, 63-pr); waves = (tile, anchor-parity). Tiles run concurrently,
// waves ping-pong-prefetch Q/V; one barrier + LDS merge per tile.

constexpr int T_LEN = 2048;
constexpr int EDIM  = 64;
constexpr int TE    = T_LEN * EDIM;
constexpr int ROWS  = 32;             // rows per tile
constexpr int NTILE = T_LEN / ROWS;   // 64 tiles per batch
constexpr int PP    = 68;             // pbuf row stride (floats): 2-way banks, 16B-aligned

typedef __attribute__((ext_vector_type(4))) float f32x4;
typedef __attribute__((ext_vector_type(8))) short bf16x8;

__device__ __forceinline__ short f2bf(float f) {
    __hip_bfloat16 h = __float2bfloat16(f);
    return __builtin_bit_cast(short, h);
}

__device__ __forceinline__ bf16x8 pack8(const f32x4& a, const f32x4& b) {
    bf16x8 r;
    r[0] = f2bf(a[0]); r[1] = f2bf(a[1]); r[2] = f2bf(a[2]); r[3] = f2bf(a[3]);
    r[4] = f2bf(b[0]); r[5] = f2bf(b[1]); r[6] = f2bf(b[2]); r[7] = f2bf(b[3]);
    return r;
}

__global__ __launch_bounds__(256, 1)
void sh2_quad(const float* __restrict__ kk, const float* __restrict__ qq,
              const float* __restrict__ vv, float* __restrict__ out, int B)
{
    __shared__ alignas(16) short slds[4][ROWS * 32];  // per-wave S scratch, 8 KB
    __shared__ float pbuf[2][ROWS][PP];               // per-tile partials, 17 KB

    const int bid = blockIdx.x;
    const int b   = bid % B;            // bid%8==b -> XCD L2 affinity per batch
    const int pr  = bid / B;            // pair index 0..31
    const int w    = threadIdx.x >> 6;
    const int wt   = w >> 1;            // 0 = tile pr (small), 1 = tile 63-pr (big)
    const int wp   = w & 1;             // anchor-tile parity
    const int lane = threadIdx.x & 63;
    const int g = lane >> 4, ln = lane & 15;

    const int t   = wt ? (NTILE - 1 - pr) : pr;
    const int y0  = ROWS * t;
    const int nat = ((4 * t + 3) >> 5) + 1;   // anchor-tiles this tile (1..8)

    const float* kb = kk + (size_t)b * TE;
    const float* qb = qq + (size_t)b * TE;
    const float* vb = vv + (size_t)b * TE;
    short* sl = slds[w];

    // K A-frags, resident for the whole tile: m = ln, k = eh*32 + 8g + i
    bf16x8 Kf[2][2];
    #pragma unroll
    for (int mt = 0; mt < 2; ++mt)
        #pragma unroll
        for (int eh = 0; eh < 2; ++eh) {
            const float* pk = kb + (size_t)(y0 + mt * 16 + ln) * EDIM + eh * 32 + g * 8;
            Kf[mt][eh] = pack8(*(const f32x4*)pk, *(const f32x4*)(pk + 4));
        }

    const f32x4 vzero = {0.f, 0.f, 0.f, 0.f};
    f32x4 acc[2][4];
    #pragma unroll
    for (int i = 0; i < 2; ++i)
        #pragma unroll
        for (int j = 0; j < 4; ++j) acc[i][j] = vzero;

    auto LOADQ = [&](f32x4 (&qr)[2][2][2], int a0) {
        #pragma unroll
        for (int nt = 0; nt < 2; ++nt)
            #pragma unroll
            for (int eh = 0; eh < 2; ++eh) {
                const float* pq = qb + (size_t)(8 * (a0 + nt * 16 + ln)) * EDIM + eh * 32 + g * 8;
                qr[nt][eh][0] = *(const f32x4*)pq;
                qr[nt][eh][1] = *(const f32x4*)(pq + 4);
            }
    };
    auto LOADV = [&](float (&vr)[4][8], int a0) {
        const float* pv = vb + (size_t)(8 * (a0 + 8 * g)) * EDIM + ln;
        #pragma unroll
        for (int i = 0; i < 8; ++i)
            #pragma unroll
            for (int et = 0; et < 4; ++et)
                vr[et][i] = pv[(size_t)(8 * i) * EDIM + et * 16];
    };

    auto COMPUTE = [&](f32x4 (&qr)[2][2][2], float (&vr)[4][8], int ai) {
        const int a0 = ai * 32;

        // stage 1: S = K · Qa^T  (2x2 of 16x16, K=64 via 2 MFMAs each)
        f32x4 S[2][2];
        #pragma unroll
        for (int mt = 0; mt < 2; ++mt)
            #pragma unroll
            for (int nt = 0; nt < 2; ++nt) {
                bf16x8 q0 = pack8(qr[nt][0][0], qr[nt][0][1]);
                bf16x8 q1 = pack8(qr[nt][1][0], qr[nt][1][1]);
                f32x4 s = vzero;
                s = __builtin_amdgcn_mfma_f32_16x16x32_bf16(Kf[mt][0], q0, s, 0, 0, 0);
                s = __builtin_amdgcn_mfma_f32_16x16x32_bf16(Kf[mt][1], q1, s, 0, 0, 0);
                S[mt][nt] = s;
            }

        // mask partial anchors (only the last anchor-tile can be partial)
        if (ai == nat - 1) {
            #pragma unroll
            for (int mt = 0; mt < 2; ++mt)
                #pragma unroll
                for (int nt = 0; nt < 2; ++nt)
                    #pragma unroll
                    for (int r = 0; r < 4; ++r) {
                        int y = y0 + mt * 16 + g * 4 + r;
                        int a = a0 + nt * 16 + ln;
                        if (8 * a > y) S[mt][nt][r] = 0.f;
                    }
        }

        // transpose S via per-wave LDS patch (XOR-swizzled 16B chunks)
        #pragma unroll
        for (int mt = 0; mt < 2; ++mt)
            #pragma unroll
            for (int nt = 0; nt < 2; ++nt)
                #pragma unroll
                for (int r = 0; r < 4; ++r) {
                    int row = mt * 16 + g * 4 + r;
                    int a   = nt * 16 + ln;
                    sl[row * 32 + (((a >> 3) ^ ((row >> 2) & 3)) << 3) + (a & 7)] = f2bf(S[mt][nt][r]);
                }

        // read back stage-2 A-frags: m = ln, k = 8g + i
        bf16x8 SA[2];
        #pragma unroll
        for (int mt = 0; mt < 2; ++mt) {
            int row = mt * 16 + ln;
            SA[mt] = *(const bf16x8*)(sl + row * 32 + ((g ^ ((row >> 2) & 3)) << 3));
        }

        // stage 2: acc += S · Va  (B-frag: n = et*16+ln (e), k = 8g+i)
        #pragma unroll
        for (int et = 0; et < 4; ++et) {
            bf16x8 Vf;
            #pragma unroll
            for (int i = 0; i < 8; ++i) Vf[i] = f2bf(vr[et][i]);
            #pragma unroll
            for (int mt = 0; mt < 2; ++mt)
                acc[mt][et] = __builtin_amdgcn_mfma_f32_16x16x32_bf16(SA[mt], Vf, acc[mt][et], 0, 0, 0);
        }
    };

    // ping-pong prefetched loop over this wave's anchor-tiles (ai = wp, wp+2, ...)
    f32x4 qA[2][2][2], qB[2][2][2];
    float vA[4][8], vB[4][8];
    int ai = wp;
    if (ai < nat) { LOADQ(qA, ai * 32); LOADV(vA, ai * 32); }
    while (ai < nat) {
        if (ai + 2 < nat) { LOADQ(qB, (ai + 2) * 32); LOADV(vB, (ai + 2) * 32); }
        COMPUTE(qA, vA, ai);
        ai += 2;
        if (ai >= nat) break;
        if (ai + 2 < nat) { LOADQ(qA, (ai + 2) * 32); LOADV(vA, (ai + 2) * 32); }
        COMPUTE(qB, vB, ai);
        ai += 2;
    }

    // merge the two parity waves of each tile through LDS, then store
    if (wp == 1) {
        #pragma unroll
        for (int mt = 0; mt < 2; ++mt)
            #pragma unroll
            for (int et = 0; et < 4; ++et)
                #pragma unroll
                for (int r = 0; r < 4; ++r)
                    pbuf[wt][mt * 16 + g * 4 + r][et * 16 + ln] = acc[mt][et][r];
    }
    __syncthreads();
    if (wp == 0) {
        float* o = out + ((size_t)b * T_LEN + y0) * EDIM;
        #pragma unroll
        for (int mt = 0; mt < 2; ++mt)
            #pragma unroll
            for (int et = 0; et < 4; ++et)
                #pragma unroll
                for (int r = 0; r < 4; ++r) {
                    int row = mt * 16 + g * 4 + r;
                    int e   = et * 16 + ln;
                    o[(size_t)row * EDIM + e] = acc[mt][et][r] + pbuf[wt][row][e];
                }
    }
}

extern "C" void kernel_launch(void* const* d_in, const int* in_sizes, int n_in,
                              void* d_out, int out_size, void* d_ws, size_t ws_size,
                              hipStream_t stream) {
    const float* kk = (const float*)d_in[0];
    const float* qq = (const float*)d_in[1];
    const float* vv = (const float*)d_in[2];
    float* o        = (float*)d_out;
    int B = in_sizes[0] / TE;
    sh2_quad<<<B * (NTILE / 2), 256, 0, stream>>>(kk, qq, vv, o, B);
}